// Round 3
// baseline (774.073 us; speedup 1.0000x reference)
//
#include <hip/hip_runtime.h>

// Problem constants (from reference): B=8, L=4096, D=1024, G=128, d=8
#define PB 8
#define PL 4096
#define PD 1024
#define PG 128
#define SEG 32
#define NSEG (PL / SEG)          // 128
#define NEPS 1e-5f

// d_out layout (flat float32): [y: B*L*D][count: B][mean: B*G][var: B*G]
#define YSZ ((size_t)PB * PL * PD)
#define COUNT_OFF (YSZ)
#define MEAN_OFF (YSZ + PB)
#define VAR_OFF (YSZ + PB + (size_t)PB * PG)

// Native 4-float vector for __builtin_nontemporal_store.
typedef float vf4 __attribute__((ext_vector_type(4)));

#define AREC ((size_t)PB * NSEG * PG)   // 131072 floats per record array

// Single fused kernel: per-(b,seg) block computes its segment aggregate
// (n,S,Q per group), publishes it with a decoupled-lookback protocol
// (flag 1 = aggregate ready, flag 2 = inclusive prefix ready), walks
// predecessors to obtain its exclusive prefix, publishes its inclusive
// prefix, then immediately produces the output tile (x re-read is L2/L3
// hot since this block just streamed it). One dispatch instead of three:
// no grid drains, no carry-array round trip.
//
// Safety: grid = 1024 blocks = exactly 4 blocks/CU at 256 thr (VGPR<=128
// via launch_bounds, ~no LDS) -> fully co-resident; blocks only spin on
// lower block IDs (AMD dispatches workgroups in increasing ID order), so
// progress is guaranteed.
__global__ __launch_bounds__(256, 4) void k_fused(
    const float* __restrict__ x,
    const void* __restrict__ prev_count,
    const float* __restrict__ prev_mean,
    const float* __restrict__ prev_var,
    const float* __restrict__ weight,
    const float* __restrict__ bias,
    const int* __restrict__ mask,
    float* __restrict__ ws,          // 6*AREC floats: agg N/S/Q, inc N/S/Q
    int* __restrict__ flags,         // PB*NSEG ints, zeroed before launch
    float* __restrict__ out)
{
    int blk = blockIdx.x;
    int b = blk >> 7;                // / NSEG
    int seg = blk & (NSEG - 1);
    int u = threadIdx.x;
    int g = u >> 1;

    float* aggN = ws;
    float* aggS = ws + AREC;
    float* aggQ = ws + 2 * AREC;
    float* incN = ws + 3 * AREC;
    float* incS = ws + 4 * AREC;
    float* incQ = ws + 5 * AREC;

    size_t row0 = (size_t)b * PL + (size_t)seg * SEG;
    const float4* xp = (const float4*)x + row0 * (PD / 4) + u;
    const int* mp = mask + b * PL + seg * SEG;

    // ---- Phase 1: segment aggregate (identical math to proven k_agg) ----
    float S = 0.f, Q = 0.f, Sb = 0.f, Qb = 0.f, nc = 0.f;
#pragma unroll 8
    for (int t = 0; t < SEG; t += 2) {
        float4 v0 = xp[(size_t)t * (PD / 4)];
        float4 v1 = xp[(size_t)(t + 1) * (PD / 4)];
        float f0 = (float)mp[t];
        float f1 = (float)mp[t + 1];
        nc += f0 + f1;
        S  = fmaf(f0, v0.x + v0.y + v0.z + v0.w, S);
        Q  = fmaf(f0, fmaf(v0.x, v0.x, fmaf(v0.y, v0.y, fmaf(v0.z, v0.z, v0.w * v0.w))), Q);
        Sb = fmaf(f1, v1.x + v1.y + v1.z + v1.w, Sb);
        Qb = fmaf(f1, fmaf(v1.x, v1.x, fmaf(v1.y, v1.y, fmaf(v1.z, v1.z, v1.w * v1.w))), Qb);
    }
    S += Sb; Q += Qb;
    S += __shfl_xor(S, 1);
    Q += __shfl_xor(Q, 1);
    float an = 8.0f * nc;            // group n-aggregate; both pair lanes hold (an,S,Q)

    int rec = blk * PG + g;
    __shared__ int s_flag;

    // ---- Phase 2: decoupled lookback -> exclusive prefix (rn,rS,rQ) ----
    float rn, rS, rQ;
    if (seg == 0) {
        // Exclusive prefix of seg 0 is the initial state from prev_*.
        const long long* p64 = (const long long*)prev_count;
        const int* p32 = (const int*)prev_count;
        long long pv = p64[b];
        float cnt = (pv >= 0 && pv < (1LL << 31)) ? (float)pv : (float)p32[b];
        float n0 = 8.0f * cnt;
        float m0 = prev_mean[b * PG + g];
        rn = n0;
        rS = m0 * n0;
        rQ = fmaf(m0, m0, prev_var[b * PG + g]) * n0;   // (var + mean^2) * n
    } else {
        // Publish aggregate (flag 1).
        if ((u & 1) == 0) {
            __hip_atomic_store(&aggN[rec], an, __ATOMIC_RELAXED, __HIP_MEMORY_SCOPE_AGENT);
            __hip_atomic_store(&aggS[rec], S,  __ATOMIC_RELAXED, __HIP_MEMORY_SCOPE_AGENT);
            __hip_atomic_store(&aggQ[rec], Q,  __ATOMIC_RELAXED, __HIP_MEMORY_SCOPE_AGENT);
        }
        __threadfence();
        __syncthreads();
        if (u == 0)
            __hip_atomic_store(&flags[blk], 1, __ATOMIC_RELEASE, __HIP_MEMORY_SCOPE_AGENT);

        // Walk predecessors (same b-chain only).
        rn = 0.f; rS = 0.f; rQ = 0.f;
        int pred = blk - 1;
        for (;;) {
            if (u == 0) {
                int f;
                while ((f = __hip_atomic_load(&flags[pred], __ATOMIC_ACQUIRE,
                                              __HIP_MEMORY_SCOPE_AGENT)) == 0) {
                    __builtin_amdgcn_s_sleep(1);
                }
                s_flag = f;
            }
            __syncthreads();
            int f = s_flag;
            __syncthreads();
            int pr = pred * PG + g;
            if (f == 2) {
                rn += __hip_atomic_load(&incN[pr], __ATOMIC_RELAXED, __HIP_MEMORY_SCOPE_AGENT);
                rS += __hip_atomic_load(&incS[pr], __ATOMIC_RELAXED, __HIP_MEMORY_SCOPE_AGENT);
                rQ += __hip_atomic_load(&incQ[pr], __ATOMIC_RELAXED, __HIP_MEMORY_SCOPE_AGENT);
                break;
            } else {
                rn += __hip_atomic_load(&aggN[pr], __ATOMIC_RELAXED, __HIP_MEMORY_SCOPE_AGENT);
                rS += __hip_atomic_load(&aggS[pr], __ATOMIC_RELAXED, __HIP_MEMORY_SCOPE_AGENT);
                rQ += __hip_atomic_load(&aggQ[pr], __ATOMIC_RELAXED, __HIP_MEMORY_SCOPE_AGENT);
                --pred;
            }
        }
    }

    // Publish inclusive prefix (flag 2); last segment also emits final stats.
    {
        float in_ = rn + an, iS = rS + S, iQ = rQ + Q;
        if ((u & 1) == 0) {
            __hip_atomic_store(&incN[rec], in_, __ATOMIC_RELAXED, __HIP_MEMORY_SCOPE_AGENT);
            __hip_atomic_store(&incS[rec], iS, __ATOMIC_RELAXED, __HIP_MEMORY_SCOPE_AGENT);
            __hip_atomic_store(&incQ[rec], iQ, __ATOMIC_RELAXED, __HIP_MEMORY_SCOPE_AGENT);
        }
        __threadfence();
        __syncthreads();
        if (u == 0)
            __hip_atomic_store(&flags[blk], 2, __ATOMIC_RELEASE, __HIP_MEMORY_SCOPE_AGENT);
        if (seg == NSEG - 1 && (u & 1) == 0) {
            float inv = 1.0f / in_;
            float mean = iS * inv;
            out[MEAN_OFF + b * PG + g] = mean;
            out[VAR_OFF + b * PG + g] = fmaf(-mean, mean, iQ * inv);
            if (g == 0) out[COUNT_OFF + b] = in_ * 0.125f;   // exact: n = 8*count
        }
    }

    // ---- Phase 3: output tile (identical math to proven k_out) ----
    {
        vf4* yp = (vf4*)out + row0 * (PD / 4) + u;
        float4 w4 = ((const float4*)weight)[u];
        float4 b4 = ((const float4*)bias)[u];
        float gx = w4.x + 1.0f, gy = w4.y + 1.0f, gz = w4.z + 1.0f, gw = w4.w + 1.0f;

        float n = rn, Sa = rS, Qa = rQ;
        float4 v0 = xp[0];
        float4 v1 = xp[PD / 4];
#pragma unroll 4
        for (int t = 0; t < SEG; ++t) {
            int tn = (t + 2 < SEG) ? (t + 2) : (SEG - 1);
            float4 vn = xp[(size_t)tn * (PD / 4)];
            float f = (float)mp[t];
            float s  = v0.x + v0.y + v0.z + v0.w;
            float ss = fmaf(v0.x, v0.x, fmaf(v0.y, v0.y, fmaf(v0.z, v0.z, v0.w * v0.w)));
            s  += __shfl_xor(s, 1);
            ss += __shfl_xor(ss, 1);
            n  = fmaf(f, 8.0f, n);
            Sa = fmaf(f, s, Sa);
            Qa = fmaf(f, ss, Qa);
            float inv  = __builtin_amdgcn_rcpf(n);
            float mean = Sa * inv;
            float var  = fmaf(-mean, mean, Qa * inv);
            float rstd = __builtin_amdgcn_rsqf(var + NEPS);
            vf4 y;
            y.x = fmaf((v0.x - mean) * rstd, gx, b4.x);
            y.y = fmaf((v0.y - mean) * rstd, gy, b4.y);
            y.z = fmaf((v0.z - mean) * rstd, gz, b4.z);
            y.w = fmaf((v0.w - mean) * rstd, gw, b4.w);
            __builtin_nontemporal_store(y, yp + (size_t)t * (PD / 4));
            v0 = v1; v1 = vn;
        }
    }
}

extern "C" void kernel_launch(void* const* d_in, const int* in_sizes, int n_in,
                              void* d_out, int out_size, void* d_ws, size_t ws_size,
                              hipStream_t stream) {
    const float* x          = (const float*)d_in[0];
    const void*  prev_count = d_in[1];
    const float* prev_mean  = (const float*)d_in[2];
    const float* prev_var   = (const float*)d_in[3];
    const float* weight     = (const float*)d_in[4];
    const float* bias       = (const float*)d_in[5];
    const int*   mask       = (const int*)d_in[6];
    float* out = (float*)d_out;
    float* ws  = (float*)d_ws;

    int* flags = (int*)(ws + 6 * AREC);   // after 3 MiB of record arrays

    // Workspace is re-poisoned by the harness each iteration: flags must be
    // zeroed before the kernel reads them. 4 KiB memset, graph-capturable.
    hipMemsetAsync(flags, 0, (size_t)PB * NSEG * sizeof(int), stream);

    hipLaunchKernelGGL(k_fused, dim3(PB * NSEG), dim3(256), 0, stream,
                       x, prev_count, prev_mean, prev_var, weight, bias, mask,
                       ws, flags, out);
}

// Round 5
// 305.599 us; speedup vs baseline: 2.5330x; 2.5330x over previous
//
#include <hip/hip_runtime.h>

// Problem constants (from reference): B=8, L=4096, D=1024, G=128, d=8
#define PB 8
#define PL 4096
#define PD 1024
#define PG 128
#define SEG 16
#define NSEG (PL / SEG)          // 256
#define NEPS 1e-5f

// d_out layout (flat float32): [y: B*L*D][count: B][mean: B*G][var: B*G]
#define YSZ ((size_t)PB * PL * PD)
#define COUNT_OFF (YSZ)
#define MEAN_OFF (YSZ + PB)
#define VAR_OFF (YSZ + PB + (size_t)PB * PG)

// Native 4-float vector for __builtin_nontemporal_store.
typedef float vf4 __attribute__((ext_vector_type(4)));

#define AREC ((size_t)PB * NSEG * PG)   // 262144 records (float4) per array

// State is raw moments per (b,g): n = #elements, S = sum(x), Q = sum(x^2),
// packed as one float4 record (n, S, Q, 0). Merge is pure addition ->
// no divide in any loop-carried chain. mean = S/n, var = Q/n - mean^2.

// Kernel 1: per-(b, seg, g) aggregate of SEG steps. Block = 256 threads =
// 128 groups x 2 halves; thread u loads float4 at row*1024 + u*4 so the
// block reads one contiguous 4KB step per t. No ordering constraints ->
// full unroll, loads fully independent. One packed float4 store per group.
__global__ __launch_bounds__(256) void k_agg(const float* __restrict__ x,
                                             const int* __restrict__ mask,
                                             float4* __restrict__ agg) {
    int blk = blockIdx.x;
    int b = blk >> 8;              // / NSEG (=256)
    int seg = blk & (NSEG - 1);
    int u = threadIdx.x;
    size_t row0 = (size_t)b * PL + (size_t)seg * SEG;
    const float4* xp = (const float4*)x + row0 * (PD / 4) + u;
    const int* mp = mask + b * PL + seg * SEG;

    float S = 0.f, Q = 0.f, Sb = 0.f, Qb = 0.f, nc = 0.f;
#pragma unroll
    for (int t = 0; t < SEG; t += 2) {
        float4 v0 = xp[(size_t)t * (PD / 4)];
        float4 v1 = xp[(size_t)(t + 1) * (PD / 4)];
        float f0 = (float)mp[t];
        float f1 = (float)mp[t + 1];
        nc += f0 + f1;
        S  = fmaf(f0, v0.x + v0.y + v0.z + v0.w, S);
        Q  = fmaf(f0, fmaf(v0.x, v0.x, fmaf(v0.y, v0.y, fmaf(v0.z, v0.z, v0.w * v0.w))), Q);
        Sb = fmaf(f1, v1.x + v1.y + v1.z + v1.w, Sb);
        Qb = fmaf(f1, fmaf(v1.x, v1.x, fmaf(v1.y, v1.y, fmaf(v1.z, v1.z, v1.w * v1.w))), Qb);
    }
    S += Sb; Q += Qb;
    S += __shfl_xor(S, 1);
    Q += __shfl_xor(Q, 1);
    if ((u & 1) == 0) {
        int idx = (b * NSEG + seg) * PG + (u >> 1);
        agg[idx] = make_float4(8.0f * nc, S, Q, 0.f);
    }
}

// Kernel 2: hierarchical exclusive prefix over NSEG segment aggregates per
// (b,g). 16 threads per (b,g) pair, 16 segments per thread: batch float4
// loads (independent -> one latency round trip), local prefix, 4-step
// __shfl_up scan across the 16-lane subgroup. Writes packed carry records
// and the final count/mean/var outputs.
__global__ __launch_bounds__(256) void k_scan(const void* __restrict__ prev_count,
                                              const float* __restrict__ prev_mean,
                                              const float* __restrict__ prev_var,
                                              const float4* __restrict__ agg,
                                              float4* __restrict__ car,
                                              float* __restrict__ out) {
    const int CH = NSEG / 16;                  // 16 segments per thread
    int t = blockIdx.x * 256 + threadIdx.x;    // PB*PG*16 = 16384 threads
    int pair = t >> 4;                         // (b,g) index, 0..1023
    int c = t & 15;                            // chunk index within pair
    int b = pair >> 7;
    int g = pair & (PG - 1);
    int idx0 = (b * NSEG + c * CH) * PG + g;

    // Batch-load the whole chunk: 16 independent float4 loads in flight.
    float4 r[CH];
#pragma unroll
    for (int i = 0; i < CH; ++i) r[i] = agg[idx0 + i * PG];

    float ln = 0.f, lS = 0.f, lQ = 0.f;
#pragma unroll
    for (int i = 0; i < CH; ++i) { ln += r[i].x; lS += r[i].y; lQ += r[i].z; }

    // Inclusive scan of chunk sums across the 16-lane subgroup.
    float sn = ln, sS = lS, sQ = lQ;
    int lane = threadIdx.x & 63;
#pragma unroll
    for (int d = 1; d < 16; d <<= 1) {
        float tn = __shfl_up(sn, d);
        float tS = __shfl_up(sS, d);
        float tQ = __shfl_up(sQ, d);
        if ((lane & 15) >= d) { sn += tn; sS += tS; sQ += tQ; }
    }

    // Base moments from prev state. prev_count is int64 per reference;
    // int32 fallback heuristic (kept identical to verified kernel).
    const long long* p64 = (const long long*)prev_count;
    const int* p32 = (const int*)prev_count;
    long long pv = p64[b];
    float cnt = (pv >= 0 && pv < (1LL << 31)) ? (float)pv : (float)p32[b];
    float n0 = 8.0f * cnt;
    float m0 = prev_mean[pair];
    float S0 = m0 * n0;
    float Q0 = fmaf(m0, m0, prev_var[pair]) * n0;   // (var + mean^2) * n

    // Exclusive offset for this chunk = base + (inclusive - local).
    float rn = n0 + (sn - ln);
    float rS = S0 + (sS - lS);
    float rQ = Q0 + (sQ - lQ);
#pragma unroll
    for (int i = 0; i < CH; ++i) {
        car[idx0 + i * PG] = make_float4(rn, rS, rQ, 0.f);
        rn += r[i].x; rS += r[i].y; rQ += r[i].z;
    }
    if (c == 15) {   // lane holding the full inclusive total
        float inv = 1.0f / rn;
        float mean = rS * inv;
        out[MEAN_OFF + pair] = mean;
        out[VAR_OFF + pair] = fmaf(-mean, mean, rQ * inv);
        if (g == 0) out[COUNT_OFF + b] = rn * 0.125f;   // exact: n = 8*count
    }
}

// Kernel 3: per-(b, seg-pair) ordered walk of SEG steps from the carry.
// Each thread owns ONE full group (8 floats = 2 float4 per step): no
// cross-lane shuffles at all. Half-block (128 thr) per segment; the two
// segments in a block are independent chains. Prefetch depth 2; y stores
// non-temporal (never re-read; don't evict x from L2/L3).
__global__ __launch_bounds__(256) void k_out(const float* __restrict__ x,
                                             const int* __restrict__ mask,
                                             const float* __restrict__ weight,
                                             const float* __restrict__ bias,
                                             const float4* __restrict__ car,
                                             float* __restrict__ out) {
    int blk = blockIdx.x;
    int b = blk >> 7;                 // / (NSEG/2)
    int sp = blk & (NSEG / 2 - 1);
    int u = threadIdx.x;
    int h = u >> 7;                   // which segment of the pair
    int g = u & (PG - 1);             // this thread's group
    int seg = sp * 2 + h;

    float4 c4 = car[(b * NSEG + seg) * PG + g];
    float n = c4.x, S = c4.y, Q = c4.z;

    size_t row0 = (size_t)b * PL + (size_t)seg * SEG;
    const float4* xp = (const float4*)x + row0 * (PD / 4) + g * 2;
    vf4* yp = (vf4*)out + row0 * (PD / 4) + g * 2;
    const int* mp = mask + b * PL + seg * SEG;

    float4 wa = ((const float4*)weight)[g * 2];
    float4 wb = ((const float4*)weight)[g * 2 + 1];
    float4 ba = ((const float4*)bias)[g * 2];
    float4 bb = ((const float4*)bias)[g * 2 + 1];
    wa.x += 1.0f; wa.y += 1.0f; wa.z += 1.0f; wa.w += 1.0f;
    wb.x += 1.0f; wb.y += 1.0f; wb.z += 1.0f; wb.w += 1.0f;

    float4 a0 = xp[0],          a1 = xp[1];
    float4 b0 = xp[PD / 4],     b1 = xp[PD / 4 + 1];
#pragma unroll 4
    for (int t = 0; t < SEG; ++t) {
        int tn = (t + 2 < SEG) ? (t + 2) : (SEG - 1);
        float4 c0 = xp[(size_t)tn * (PD / 4)];
        float4 c1 = xp[(size_t)tn * (PD / 4) + 1];
        float f = (float)mp[t];
        float s  = (a0.x + a0.y) + (a0.z + a0.w) + (a1.x + a1.y) + (a1.z + a1.w);
        float ss = fmaf(a0.x, a0.x, fmaf(a0.y, a0.y, fmaf(a0.z, a0.z, a0.w * a0.w)));
        ss = fmaf(a1.x, a1.x, fmaf(a1.y, a1.y, fmaf(a1.z, a1.z, fmaf(a1.w, a1.w, ss))));
        n = fmaf(f, 8.0f, n);
        S = fmaf(f, s, S);
        Q = fmaf(f, ss, Q);
        float inv  = __builtin_amdgcn_rcpf(n);
        float mean = S * inv;
        float var  = fmaf(-mean, mean, Q * inv);
        float rstd = __builtin_amdgcn_rsqf(var + NEPS);
        vf4 y0, y1;
        y0.x = fmaf((a0.x - mean) * rstd, wa.x, ba.x);
        y0.y = fmaf((a0.y - mean) * rstd, wa.y, ba.y);
        y0.z = fmaf((a0.z - mean) * rstd, wa.z, ba.z);
        y0.w = fmaf((a0.w - mean) * rstd, wa.w, ba.w);
        y1.x = fmaf((a1.x - mean) * rstd, wb.x, bb.x);
        y1.y = fmaf((a1.y - mean) * rstd, wb.y, bb.y);
        y1.z = fmaf((a1.z - mean) * rstd, wb.z, bb.z);
        y1.w = fmaf((a1.w - mean) * rstd, wb.w, bb.w);
        __builtin_nontemporal_store(y0, yp + (size_t)t * (PD / 4));
        __builtin_nontemporal_store(y1, yp + (size_t)t * (PD / 4) + 1);
        a0 = b0; a1 = b1; b0 = c0; b1 = c1;
    }
}

extern "C" void kernel_launch(void* const* d_in, const int* in_sizes, int n_in,
                              void* d_out, int out_size, void* d_ws, size_t ws_size,
                              hipStream_t stream) {
    const float* x          = (const float*)d_in[0];
    const void*  prev_count = d_in[1];
    const float* prev_mean  = (const float*)d_in[2];
    const float* prev_var   = (const float*)d_in[3];
    const float* weight     = (const float*)d_in[4];
    const float* bias       = (const float*)d_in[5];
    const int*   mask       = (const int*)d_in[6];
    float* out = (float*)d_out;

    float4* agg = (float4*)d_ws;            // 4 MiB
    float4* car = agg + AREC;               // 4 MiB

    hipLaunchKernelGGL(k_agg, dim3(PB * NSEG), dim3(256), 0, stream,
                       x, mask, agg);
    hipLaunchKernelGGL(k_scan, dim3((PB * PG * 16) / 256), dim3(256), 0, stream,
                       prev_count, prev_mean, prev_var, agg, car, out);
    hipLaunchKernelGGL(k_out, dim3(PB * (NSEG / 2)), dim3(256), 0, stream,
                       x, mask, weight, bias, car, out);
}

// Round 6
// 265.275 us; speedup vs baseline: 2.9180x; 1.1520x over previous
//
#include <hip/hip_runtime.h>

// Problem constants (from reference): B=8, L=4096, D=1024, G=128, d=8
#define PB 8
#define PL 4096
#define PD 1024
#define PG 128
#define SEG 32
#define NSEG (PL / SEG)          // 128
#define NEPS 1e-5f

// d_out layout (flat float32): [y: B*L*D][count: B][mean: B*G][var: B*G]
#define YSZ ((size_t)PB * PL * PD)
#define COUNT_OFF (YSZ)
#define MEAN_OFF (YSZ + PB)
#define VAR_OFF (YSZ + PB + (size_t)PB * PG)

// Native 4-float vector for __builtin_nontemporal_store.
typedef float vf4 __attribute__((ext_vector_type(4)));

// State is raw moments per (b,g): n = #elements, S = sum(x), Q = sum(x^2),
// packed as one float4 record (n, S, Q, 0). Merge is pure addition ->
// no divide in any loop-carried chain. mean = S/n, var = Q/n - mean^2.

// Kernel 1 (= round-2 proven k_agg, packed store): per-(b, seg, g)
// aggregate of SEG steps. Block = 256 threads = 128 groups x 2 halves;
// thread u loads float4 at row*1024 + u*4 so the block reads one
// contiguous 4KB step per t. Deep unroll, loads fully independent.
__global__ __launch_bounds__(256) void k_agg(const float* __restrict__ x,
                                             const int* __restrict__ mask,
                                             float4* __restrict__ agg) {
    int blk = blockIdx.x;
    int b = blk >> 7;              // / NSEG
    int seg = blk & (NSEG - 1);
    int u = threadIdx.x;
    size_t row0 = (size_t)b * PL + (size_t)seg * SEG;
    const float4* xp = (const float4*)x + row0 * (PD / 4) + u;
    const int* mp = mask + b * PL + seg * SEG;

    float S = 0.f, Q = 0.f, Sb = 0.f, Qb = 0.f, nc = 0.f;
#pragma unroll 8
    for (int t = 0; t < SEG; t += 2) {
        float4 v0 = xp[(size_t)t * (PD / 4)];
        float4 v1 = xp[(size_t)(t + 1) * (PD / 4)];
        float f0 = (float)mp[t];
        float f1 = (float)mp[t + 1];
        nc += f0 + f1;
        S  = fmaf(f0, v0.x + v0.y + v0.z + v0.w, S);
        Q  = fmaf(f0, fmaf(v0.x, v0.x, fmaf(v0.y, v0.y, fmaf(v0.z, v0.z, v0.w * v0.w))), Q);
        Sb = fmaf(f1, v1.x + v1.y + v1.z + v1.w, Sb);
        Qb = fmaf(f1, fmaf(v1.x, v1.x, fmaf(v1.y, v1.y, fmaf(v1.z, v1.z, v1.w * v1.w))), Qb);
    }
    S += Sb; Q += Qb;
    S += __shfl_xor(S, 1);
    Q += __shfl_xor(Q, 1);
    if ((u & 1) == 0) {
        int idx = (b * NSEG + seg) * PG + (u >> 1);
        agg[idx] = make_float4(8.0f * nc, S, Q, 0.f);
    }
}

// Kernel 2 (= round-2 proven k_out + inline prefix): per-(b, seg) block.
// Prefix over preceding segment aggregates computed in-block from the
// L2/L3-resident agg array: pair-lane parity split (even lane sums even
// segments, odd lane odd segments), <=64 independent 16B loads/thread,
// one __shfl_xor combine. Replaces k_scan + carry array -> one fewer
// dispatch/drain. seg==NSEG-1 blocks' end-state IS the final state ->
// they emit count/mean/var. Ordered walk identical to round-2 k_out:
// contiguous per-instruction loads/stores, prefetch depth 2, NT stores.
__global__ __launch_bounds__(256) void k_out(const float* __restrict__ x,
                                             const int* __restrict__ mask,
                                             const float* __restrict__ weight,
                                             const float* __restrict__ bias,
                                             const void* __restrict__ prev_count,
                                             const float* __restrict__ prev_mean,
                                             const float* __restrict__ prev_var,
                                             const float4* __restrict__ agg,
                                             float* __restrict__ out) {
    int blk = blockIdx.x;
    int b = blk >> 7;
    int seg = blk & (NSEG - 1);
    int u = threadIdx.x;
    int g = u >> 1;
    int p = u & 1;

    // ---- Inline exclusive prefix for (b, g) over segments < seg ----
    float pn = 0.f, pS = 0.f, pQ = 0.f;
    const float4* ab = agg + b * NSEG * PG + g;
#pragma unroll 4
    for (int s = p; s < seg; s += 2) {
        float4 r = ab[s * PG];
        pn += r.x; pS += r.y; pQ += r.z;
    }
    pn += __shfl_xor(pn, 1);
    pS += __shfl_xor(pS, 1);
    pQ += __shfl_xor(pQ, 1);

    // Base moments from prev state. prev_count is int64 per reference;
    // int32 fallback heuristic (kept identical to verified kernel).
    const long long* p64 = (const long long*)prev_count;
    const int* p32 = (const int*)prev_count;
    long long pv = p64[b];
    float cnt = (pv >= 0 && pv < (1LL << 31)) ? (float)pv : (float)p32[b];
    float n0 = 8.0f * cnt;
    float m0 = prev_mean[b * PG + g];
    float n = n0 + pn;
    float S = fmaf(m0, n0, pS);
    float Q = fmaf(fmaf(m0, m0, prev_var[b * PG + g]), n0, pQ); // (var+mean^2)*n

    size_t row0 = (size_t)b * PL + (size_t)seg * SEG;
    const float4* xp = (const float4*)x + row0 * (PD / 4) + u;
    vf4* yp = (vf4*)out + row0 * (PD / 4) + u;
    const int* mp = mask + b * PL + seg * SEG;

    float4 w4 = ((const float4*)weight)[u];
    float4 b4 = ((const float4*)bias)[u];
    float gx = w4.x + 1.0f, gy = w4.y + 1.0f, gz = w4.z + 1.0f, gw = w4.w + 1.0f;

    float4 v0 = xp[0];
    float4 v1 = xp[PD / 4];
#pragma unroll 4
    for (int t = 0; t < SEG; ++t) {
        int tn = (t + 2 < SEG) ? (t + 2) : (SEG - 1);
        float4 vn = xp[(size_t)tn * (PD / 4)];
        float f = (float)mp[t];
        float s  = v0.x + v0.y + v0.z + v0.w;
        float ss = fmaf(v0.x, v0.x, fmaf(v0.y, v0.y, fmaf(v0.z, v0.z, v0.w * v0.w)));
        s  += __shfl_xor(s, 1);
        ss += __shfl_xor(ss, 1);
        n = fmaf(f, 8.0f, n);
        S = fmaf(f, s, S);
        Q = fmaf(f, ss, Q);
        float inv  = __builtin_amdgcn_rcpf(n);
        float mean = S * inv;
        float var  = fmaf(-mean, mean, Q * inv);
        float rstd = __builtin_amdgcn_rsqf(var + NEPS);
        vf4 y;
        y.x = fmaf((v0.x - mean) * rstd, gx, b4.x);
        y.y = fmaf((v0.y - mean) * rstd, gy, b4.y);
        y.z = fmaf((v0.z - mean) * rstd, gz, b4.z);
        y.w = fmaf((v0.w - mean) * rstd, gw, b4.w);
        __builtin_nontemporal_store(y, yp + (size_t)t * (PD / 4));
        v0 = v1; v1 = vn;
    }

    // Final stats: the last segment's end-state is the reference's final
    // (count, mean, var). Both pair lanes hold identical n,S,Q.
    if (seg == NSEG - 1 && p == 0) {
        float inv = 1.0f / n;
        float mean = S * inv;
        out[MEAN_OFF + b * PG + g] = mean;
        out[VAR_OFF + b * PG + g] = fmaf(-mean, mean, Q * inv);
        if (g == 0) out[COUNT_OFF + b] = n * 0.125f;   // exact: n = 8*count
    }
}

extern "C" void kernel_launch(void* const* d_in, const int* in_sizes, int n_in,
                              void* d_out, int out_size, void* d_ws, size_t ws_size,
                              hipStream_t stream) {
    const float* x          = (const float*)d_in[0];
    const void*  prev_count = d_in[1];
    const float* prev_mean  = (const float*)d_in[2];
    const float* prev_var   = (const float*)d_in[3];
    const float* weight     = (const float*)d_in[4];
    const float* bias       = (const float*)d_in[5];
    const int*   mask       = (const int*)d_in[6];
    float* out = (float*)d_out;

    float4* agg = (float4*)d_ws;   // PB*NSEG*PG float4 = 2 MiB

    hipLaunchKernelGGL(k_agg, dim3(PB * NSEG), dim3(256), 0, stream,
                       x, mask, agg);
    hipLaunchKernelGGL(k_out, dim3(PB * NSEG), dim3(256), 0, stream,
                       x, mask, weight, bias,
                       prev_count, prev_mean, prev_var, agg, out);
}